// Round 3
// baseline (237.179 us; speedup 1.0000x reference)
//
#include <hip/hip_runtime.h>

#define BATCH 32
#define SEQ 512
#define CH 384
#define MAXL 4096
#define CH4 96            // float4 per channel row
#define ROWS 32           // output rows (t positions) per block
#define THREADS 256
#define NT (ROWS * CH4)   // 3072 float4 per block

typedef float v4f __attribute__((ext_vector_type(4)));

// Fully fused length-regulator:
//  - per-block redundant cumsum of this batch's 512 durations (LDS Hillis-Steele)
//  - searchsorted(ends, t, 'right') via 10-step binary search in LDS (one thread/row)
//    NOTE: answer space is [0,512] = 513 values -> ceil(log2(513)) = 10 iters.
//    9 iters leaves hi-lo==1 unresolved (R2 bug, absmax 5.8).
//  - 32 rows x 384 ch expanded write, nontemporal dwordx4 (write-once output)
//  - mask written as 0.0/1.0 floats
__global__ __launch_bounds__(THREADS) void lr_fused_kernel(
    const v4f* __restrict__ x,
    const int2* __restrict__ dur2,
    const int* __restrict__ max_len_p,
    v4f* __restrict__ out,
    float* __restrict__ out_mask)
{
    __shared__ int s_scan[THREADS];
    __shared__ int s_end[SEQ];
    __shared__ int s_idx[ROWS];

    const int tid = threadIdx.x;
    const int r0 = blockIdx.x * ROWS;     // global output row = b*4096 + t0
    const int b  = r0 >> 12;
    const int t0 = r0 & (MAXL - 1);
    const int maxlen = max_len_p[0];

    // --- cumsum of 512 durations with 256 threads (pairwise) ---
    int2 d = dur2[b * (SEQ / 2) + tid];   // coalesced 8B loads, L2-hot (64 KB total)
    s_scan[tid] = d.x + d.y;
    __syncthreads();
    #pragma unroll
    for (int off = 1; off < THREADS; off <<= 1) {
        int v = (tid >= off) ? s_scan[tid - off] : 0;
        __syncthreads();
        s_scan[tid] += v;
        __syncthreads();
    }
    int incl = s_scan[tid];                       // inclusive over pairs
    s_end[2 * tid]     = min(incl - d.y, maxlen); // clip like reference
    s_end[2 * tid + 1] = min(incl, maxlen);
    __syncthreads();

    const int total = s_end[SEQ - 1];

    // --- searchsorted for this block's 32 t values ---
    if (tid < ROWS) {
        int t = t0 + tid;
        int lo = 0, hi = SEQ;                     // answer in [0,512]
        #pragma unroll
        for (int it = 0; it < 10; ++it) {         // 10 = ceil(log2(513))
            int mid = (lo + hi) >> 1;
            if (s_end[mid] <= t) lo = mid + 1; else hi = mid;
        }
        bool masked = (t >= total);
        s_idx[tid] = masked ? -1 : min(lo, SEQ - 1);  // ref clips idx to S-1
        out_mask[r0 + tid] = masked ? 1.0f : 0.0f;
    }
    __syncthreads();

    // --- expanded write: 3072 float4, 12 per thread, contiguous per block ---
    const v4f* xb = x + (size_t)b * SEQ * CH4;
    v4f* ob = out + (size_t)r0 * CH4;
    #pragma unroll
    for (int k = 0; k < NT / THREADS; ++k) {
        int local = tid + k * THREADS;            // 0..3071
        int lr = local / CH4;                     // row in block (magic-mul)
        int c4 = local - lr * CH4;                // 0..95
        int idx = s_idx[lr];
        v4f v = (v4f){0.f, 0.f, 0.f, 0.f};
        if (idx >= 0) v = xb[idx * CH4 + c4];     // cached read, heavy L2 reuse
        __builtin_nontemporal_store(v, &ob[local]); // write-once: keep L2 for x
    }
}

extern "C" void kernel_launch(void* const* d_in, const int* in_sizes, int n_in,
                              void* d_out, int out_size, void* d_ws, size_t ws_size,
                              hipStream_t stream) {
    const v4f* x = (const v4f*)d_in[0];
    const int2* dur2 = (const int2*)d_in[1];
    const int* max_len_p = (const int*)d_in[2];
    float* out = (float*)d_out;
    float* out_mask = out + (size_t)BATCH * MAXL * CH;

    lr_fused_kernel<<<(BATCH * MAXL) / ROWS, THREADS, 0, stream>>>(
        x, dur2, max_len_p, (v4f*)out, out_mask);
}